// Round 1
// baseline (236.178 us; speedup 1.0000x reference)
//
#include <hip/hip_runtime.h>

// Problem constants
#define E_  100
#define F_  10
#define D_  100
#define N_  8192
#define TN  256          // n-tile per block
#define NTILES (N_ / TN) // 32

// Per-estimator combined-parameter layout in d_ws (floats), 16B-aligned blocks:
//   [0..199]   Whi  (2 x 100, a-major: a*100+d)
//   [200..299] bhi  (100)
//   [300..499] Wlo  (2 x 100)
//   [500..599] blo  (100)
//   [600..619] Wenc (10 x 2, f-major: f*2+g)
//   [620..621] benc (2)
#define OFF_WHI  0
#define OFF_BHI  200
#define OFF_WLO  300
#define OFF_BLO  500
#define OFF_WENC 600
#define OFF_BENC 620
#define WS_PER_E 624     // padded, multiple of 4 -> per-e base stays 16B aligned

// ---------------------------------------------------------------------------
// Kernel 1: fold each estimator's linear MLPs into single affine maps.
// One block per estimator, 128 threads. Total work ~ O(100 * 25k MACs): trivial.
// ---------------------------------------------------------------------------
__global__ __launch_bounds__(128) void combine_kernel(
    const float* __restrict__ enc_w0, const float* __restrict__ enc_b0,
    const float* __restrict__ enc_w1, const float* __restrict__ enc_b1,
    const float* __restrict__ enc_w2, const float* __restrict__ enc_b2,
    const float* __restrict__ hi_w0,  const float* __restrict__ hi_b0,
    const float* __restrict__ hi_w1,  const float* __restrict__ hi_b1,
    const float* __restrict__ hi_w2,  const float* __restrict__ hi_b2,
    const float* __restrict__ lo_w0,  const float* __restrict__ lo_b0,
    const float* __restrict__ lo_w1,  const float* __restrict__ lo_b1,
    const float* __restrict__ lo_w2,  const float* __restrict__ lo_b2,
    float* __restrict__ ws)
{
    const int e = blockIdx.x;
    const int t = threadIdx.x;
    float* wsE = ws + (size_t)e * WS_PER_E;

    // ---------------- encoder: (10x5)@(5x2)@(2x2) -------------------------
    {
        const float* w0 = enc_w0 + e * 50;  // 10x5
        const float* w1 = enc_w1 + e * 10;  // 5x2
        const float* w2 = enc_w2 + e * 4;   // 2x2
        const float* b0 = enc_b0 + e * 5;
        const float* b1 = enc_b1 + e * 2;
        const float* b2 = enc_b2 + e * 2;

        __shared__ float sW01[20];  // [f][g] = w0@w1
        __shared__ float sB01[2];
        if (t < 20) {
            int f = t >> 1, g = t & 1;
            float s = 0.f;
            for (int k = 0; k < 5; ++k) s += w0[f * 5 + k] * w1[k * 2 + g];
            sW01[t] = s;
        }
        if (t < 2) {
            float s = b1[t];
            for (int k = 0; k < 5; ++k) s += b0[k] * w1[k * 2 + t];
            sB01[t] = s;
        }
        __syncthreads();
        if (t < 20) {
            int f = t >> 1, g2 = t & 1;
            wsE[OFF_WENC + t] = sW01[f * 2 + 0] * w2[0 * 2 + g2]
                              + sW01[f * 2 + 1] * w2[1 * 2 + g2];
        }
        if (t < 2) {
            wsE[OFF_BENC + t] = sB01[0] * w2[0 * 2 + t] + sB01[1] * w2[1 * 2 + t] + b2[t];
        }
        __syncthreads();
    }

    // ---------------- decoders: (2x25)@(25x50)@(50x100) -------------------
    __shared__ float sT[100];  // [a][c] = w0@w1  (2 x 50)
    __shared__ float sU[50];   // bias through layer 1
    for (int dec = 0; dec < 2; ++dec) {
        const float* w0 = (dec ? lo_w0 : hi_w0) + e * 50;    // 2x25
        const float* w1 = (dec ? lo_w1 : hi_w1) + e * 1250;  // 25x50
        const float* w2 = (dec ? lo_w2 : hi_w2) + e * 5000;  // 50x100
        const float* b0 = (dec ? lo_b0 : hi_b0) + e * 25;
        const float* b1 = (dec ? lo_b1 : hi_b1) + e * 50;
        const float* b2 = (dec ? lo_b2 : hi_b2) + e * 100;
        float* W = wsE + (dec ? OFF_WLO : OFF_WHI);
        float* B = wsE + (dec ? OFF_BLO : OFF_BHI);

        for (int i = t; i < 100; i += blockDim.x) {
            int a = i / 50, c = i % 50;
            float s = 0.f;
            for (int b = 0; b < 25; ++b) s += w0[a * 25 + b] * w1[b * 50 + c];
            sT[i] = s;
        }
        for (int i = t; i < 50; i += blockDim.x) {
            float s = b1[i];
            for (int b = 0; b < 25; ++b) s += b0[b] * w1[b * 50 + i];
            sU[i] = s;
        }
        __syncthreads();
        for (int i = t; i < 200; i += blockDim.x) {
            int a = i / 100, d = i % 100;
            float s = 0.f;
            for (int c = 0; c < 50; ++c) s += sT[a * 50 + c] * w2[c * 100 + d];
            W[i] = s;
        }
        for (int i = t; i < 100; i += blockDim.x) {
            float s = b2[i];
            for (int c = 0; c < 50; ++c) s += sU[c] * w2[c * 100 + i];
            B[i] = s;
        }
        __syncthreads();  // before sT/sU reuse by next decoder
    }
}

// ---------------------------------------------------------------------------
// Kernel 2: per (e, n-tile): gather -> z (rank-2 latent) -> write 2*100 outs.
// Writes are lane-consecutive float4 -> fully coalesced. Memory-bound on the
// 655 MB of output stores.
// ---------------------------------------------------------------------------
__global__ __launch_bounds__(256) void rancoders_main(
    const float* __restrict__ inputs,      // [N, D]
    const int*   __restrict__ randsamples, // [E, F]
    const float* __restrict__ ws,
    float* __restrict__ out)               // [hi: E*N*D][lo: E*N*D]
{
    const int e    = blockIdx.x >> 5;       // / NTILES
    const int tile = blockIdx.x & (NTILES - 1);
    const int n0   = tile * TN;
    const int t    = threadIdx.x;

    __shared__ __align__(16) float sP[WS_PER_E];
    __shared__ int   sIdx[F_];
    __shared__ float sZ[TN * 2];

    const float* wsE = ws + (size_t)e * WS_PER_E;
    for (int i = t; i < 622; i += 256) sP[i] = wsE[i];
    if (t < F_) sIdx[t] = randsamples[e * F_ + t];
    __syncthreads();

    // ---- phase 1: latent z for this thread's n ----
    {
        const int n = n0 + t;
        const float* row = inputs + (size_t)n * D_;
        float z0 = sP[OFF_BENC + 0];
        float z1 = sP[OFF_BENC + 1];
#pragma unroll
        for (int f = 0; f < F_; ++f) {
            float v = row[sIdx[f]];
            z0 += v * sP[OFF_WENC + 2 * f + 0];
            z1 += v * sP[OFF_WENC + 2 * f + 1];
        }
        sZ[2 * t + 0] = z0;
        sZ[2 * t + 1] = z1;
    }
    __syncthreads();

    // ---- phase 2: decode + coalesced float4 stores ----
    float* out_hi = out + (size_t)(e * N_ + n0) * D_;
    float* out_lo = out + (size_t)E_ * N_ * D_ + (size_t)(e * N_ + n0) * D_;

    // TN*D_ = 25600 floats = 6400 float4; 25 iterations per thread.
    for (int q = t; q < (TN * D_) / 4; q += 256) {
        const int nl = q / 25;        // local n (D_/4 = 25 quads per row)
        const int dq = q % 25;
        const int d  = dq * 4;
        const float z0 = sZ[2 * nl + 0];
        const float z1 = sZ[2 * nl + 1];

        float4 w0h = *(const float4*)&sP[OFF_WHI + d];
        float4 w1h = *(const float4*)&sP[OFF_WHI + 100 + d];
        float4 bh  = *(const float4*)&sP[OFF_BHI + d];
        float4 o;
        o.x = z0 * w0h.x + z1 * w1h.x + bh.x;
        o.y = z0 * w0h.y + z1 * w1h.y + bh.y;
        o.z = z0 * w0h.z + z1 * w1h.z + bh.z;
        o.w = z0 * w0h.w + z1 * w1h.w + bh.w;
        *(float4*)&out_hi[(size_t)q * 4] = o;

        float4 w0l = *(const float4*)&sP[OFF_WLO + d];
        float4 w1l = *(const float4*)&sP[OFF_WLO + 100 + d];
        float4 bl  = *(const float4*)&sP[OFF_BLO + d];
        o.x = z0 * w0l.x + z1 * w1l.x + bl.x;
        o.y = z0 * w0l.y + z1 * w1l.y + bl.y;
        o.z = z0 * w0l.z + z1 * w1l.z + bl.z;
        o.w = z0 * w0l.w + z1 * w1l.w + bl.w;
        *(float4*)&out_lo[(size_t)q * 4] = o;
    }
}

extern "C" void kernel_launch(void* const* d_in, const int* in_sizes, int n_in,
                              void* d_out, int out_size, void* d_ws, size_t ws_size,
                              hipStream_t stream) {
    // setup_inputs() dict order:
    // 0 inputs, 1 randsamples,
    // then for i in 0..2: enc_w{i}, enc_b{i}, hi_w{i}, hi_b{i}, lo_w{i}, lo_b{i}
    const float* inputs      = (const float*)d_in[0];
    const int*   randsamples = (const int*)d_in[1];
    const float* enc_w0 = (const float*)d_in[2];
    const float* enc_b0 = (const float*)d_in[3];
    const float* hi_w0  = (const float*)d_in[4];
    const float* hi_b0  = (const float*)d_in[5];
    const float* lo_w0  = (const float*)d_in[6];
    const float* lo_b0  = (const float*)d_in[7];
    const float* enc_w1 = (const float*)d_in[8];
    const float* enc_b1 = (const float*)d_in[9];
    const float* hi_w1  = (const float*)d_in[10];
    const float* hi_b1  = (const float*)d_in[11];
    const float* lo_w1  = (const float*)d_in[12];
    const float* lo_b1  = (const float*)d_in[13];
    const float* enc_w2 = (const float*)d_in[14];
    const float* enc_b2 = (const float*)d_in[15];
    const float* hi_w2  = (const float*)d_in[16];
    const float* hi_b2  = (const float*)d_in[17];
    const float* lo_w2  = (const float*)d_in[18];
    const float* lo_b2  = (const float*)d_in[19];

    float* ws  = (float*)d_ws;   // needs E_*WS_PER_E*4 = 249,600 bytes
    float* out = (float*)d_out;

    combine_kernel<<<E_, 128, 0, stream>>>(
        enc_w0, enc_b0, enc_w1, enc_b1, enc_w2, enc_b2,
        hi_w0, hi_b0, hi_w1, hi_b1, hi_w2, hi_b2,
        lo_w0, lo_b0, lo_w1, lo_b1, lo_w2, lo_b2, ws);

    rancoders_main<<<E_ * NTILES, 256, 0, stream>>>(inputs, randsamples, ws, out);
}

// Round 3
// 177.774 us; speedup vs baseline: 1.3285x; 1.3285x over previous
//
#include <hip/hip_runtime.h>

// Problem constants
#define E_  100
#define F_  10
#define D_  100
#define N_  8192
#define TN  256          // n-tile per block
#define NTILES (N_ / TN) // 32

typedef float f32x4 __attribute__((ext_vector_type(4)));

// Per-estimator combined-parameter layout in d_ws (floats):
//   [0..199]   Whi  (2 x 100, a-major: a*100+d)
//   [200..299] bhi  (100)
//   [300..499] Wlo  (2 x 100)
//   [500..599] blo  (100)
//   [600..619] Wenc (10 x 2, f-major: f*2+g)
//   [620..621] benc (2)
#define OFF_WHI  0
#define OFF_BHI  200
#define OFF_WLO  300
#define OFF_BLO  500
#define OFF_WENC 600
#define OFF_BENC 620
#define WS_PER_E 624     // multiple of 4 -> per-e base stays 16B aligned

// ---------------------------------------------------------------------------
// Kernel 1: fold each estimator's linear MLPs into single affine maps.
// One block per estimator, 128 threads. Trivial cost.
// ---------------------------------------------------------------------------
__global__ __launch_bounds__(128) void combine_kernel(
    const float* __restrict__ enc_w0, const float* __restrict__ enc_b0,
    const float* __restrict__ enc_w1, const float* __restrict__ enc_b1,
    const float* __restrict__ enc_w2, const float* __restrict__ enc_b2,
    const float* __restrict__ hi_w0,  const float* __restrict__ hi_b0,
    const float* __restrict__ hi_w1,  const float* __restrict__ hi_b1,
    const float* __restrict__ hi_w2,  const float* __restrict__ hi_b2,
    const float* __restrict__ lo_w0,  const float* __restrict__ lo_b0,
    const float* __restrict__ lo_w1,  const float* __restrict__ lo_b1,
    const float* __restrict__ lo_w2,  const float* __restrict__ lo_b2,
    float* __restrict__ ws)
{
    const int e = blockIdx.x;
    const int t = threadIdx.x;
    float* wsE = ws + (size_t)e * WS_PER_E;

    // ---------------- encoder: (10x5)@(5x2)@(2x2) -------------------------
    {
        const float* w0 = enc_w0 + e * 50;  // 10x5
        const float* w1 = enc_w1 + e * 10;  // 5x2
        const float* w2 = enc_w2 + e * 4;   // 2x2
        const float* b0 = enc_b0 + e * 5;
        const float* b1 = enc_b1 + e * 2;
        const float* b2 = enc_b2 + e * 2;

        __shared__ float sW01[20];  // [f][g] = w0@w1
        __shared__ float sB01[2];
        if (t < 20) {
            int f = t >> 1, g = t & 1;
            float s = 0.f;
            for (int k = 0; k < 5; ++k) s += w0[f * 5 + k] * w1[k * 2 + g];
            sW01[t] = s;
        }
        if (t < 2) {
            float s = b1[t];
            for (int k = 0; k < 5; ++k) s += b0[k] * w1[k * 2 + t];
            sB01[t] = s;
        }
        __syncthreads();
        if (t < 20) {
            int f = t >> 1, g2 = t & 1;
            wsE[OFF_WENC + t] = sW01[f * 2 + 0] * w2[0 * 2 + g2]
                              + sW01[f * 2 + 1] * w2[1 * 2 + g2];
        }
        if (t < 2) {
            wsE[OFF_BENC + t] = sB01[0] * w2[0 * 2 + t] + sB01[1] * w2[1 * 2 + t] + b2[t];
        }
        __syncthreads();
    }

    // ---------------- decoders: (2x25)@(25x50)@(50x100) -------------------
    __shared__ float sT[100];  // [a][c] = w0@w1  (2 x 50)
    __shared__ float sU[50];   // bias through layer 1
    for (int dec = 0; dec < 2; ++dec) {
        const float* w0 = (dec ? lo_w0 : hi_w0) + e * 50;    // 2x25
        const float* w1 = (dec ? lo_w1 : hi_w1) + e * 1250;  // 25x50
        const float* w2 = (dec ? lo_w2 : hi_w2) + e * 5000;  // 50x100
        const float* b0 = (dec ? lo_b0 : hi_b0) + e * 25;
        const float* b1 = (dec ? lo_b1 : hi_b1) + e * 50;
        const float* b2 = (dec ? lo_b2 : hi_b2) + e * 100;
        float* W = wsE + (dec ? OFF_WLO : OFF_WHI);
        float* B = wsE + (dec ? OFF_BLO : OFF_BHI);

        for (int i = t; i < 100; i += blockDim.x) {
            int a = i / 50, c = i % 50;
            float s = 0.f;
            for (int b = 0; b < 25; ++b) s += w0[a * 25 + b] * w1[b * 50 + c];
            sT[i] = s;
        }
        for (int i = t; i < 50; i += blockDim.x) {
            float s = b1[i];
            for (int b = 0; b < 25; ++b) s += b0[b] * w1[b * 50 + i];
            sU[i] = s;
        }
        __syncthreads();
        for (int i = t; i < 200; i += blockDim.x) {
            int a = i / 100, d = i % 100;
            float s = 0.f;
            for (int c = 0; c < 50; ++c) s += sT[a * 50 + c] * w2[c * 100 + d];
            W[i] = s;
        }
        for (int i = t; i < 100; i += blockDim.x) {
            float s = b2[i];
            for (int c = 0; c < 50; ++c) s += sU[c] * w2[c * 100 + i];
            B[i] = s;
        }
        __syncthreads();  // before sT/sU reuse by next decoder
    }
}

// ---------------------------------------------------------------------------
// Kernel 2: per (e, n-tile): gather -> z (rank-2 latent) -> write 2*100 outs.
// Phase 2: thread owns a FIXED column-quad dq (weights live in registers);
// iterates over rows. Stores stay contiguous; LDS traffic is a 2-float
// broadcast per iteration. Nontemporal stores (output is pure streaming).
// ---------------------------------------------------------------------------
__global__ __launch_bounds__(256) void rancoders_main(
    const float* __restrict__ inputs,      // [N, D]
    const int*   __restrict__ randsamples, // [E, F]
    const float* __restrict__ ws,
    float* __restrict__ out)               // [hi: E*N*D][lo: E*N*D]
{
    const int e    = blockIdx.x >> 5;       // / NTILES
    const int tile = blockIdx.x & (NTILES - 1);
    const int n0   = tile * TN;
    const int t    = threadIdx.x;

    __shared__ __align__(16) float sP[WS_PER_E];
    __shared__ int   sIdx[F_];
    __shared__ float sZ[TN * 2];

    const float* wsE = ws + (size_t)e * WS_PER_E;
    for (int i = t; i < 622; i += 256) sP[i] = wsE[i];
    if (t < F_) sIdx[t] = randsamples[e * F_ + t];
    __syncthreads();

    // ---- phase 1: latent z for this thread's row ----
    {
        const int n = n0 + t;
        const float* row = inputs + (size_t)n * D_;
        float z0 = sP[OFF_BENC + 0];
        float z1 = sP[OFF_BENC + 1];
#pragma unroll
        for (int f = 0; f < F_; ++f) {
            float v = row[sIdx[f]];
            z0 += v * sP[OFF_WENC + 2 * f + 0];
            z1 += v * sP[OFF_WENC + 2 * f + 1];
        }
        sZ[2 * t + 0] = z0;
        sZ[2 * t + 1] = z1;
    }
    __syncthreads();

    // ---- phase 2: fixed column-quad per thread, weights in registers ----
    const int dq   = t & 31;          // 0..31; 25..31 are masked lanes
    const int rb   = t >> 5;          // row sub-index 0..7
    const bool act = (dq < 25);
    const int d    = (act ? dq : 24) * 4;   // clamp for safe LDS reads

    const f32x4 w0h = *(const f32x4*)&sP[OFF_WHI + d];
    const f32x4 w1h = *(const f32x4*)&sP[OFF_WHI + 100 + d];
    const f32x4 bh  = *(const f32x4*)&sP[OFF_BHI + d];
    const f32x4 w0l = *(const f32x4*)&sP[OFF_WLO + d];
    const f32x4 w1l = *(const f32x4*)&sP[OFF_WLO + 100 + d];
    const f32x4 bl  = *(const f32x4*)&sP[OFF_BLO + d];

    float* out_hi = out + (size_t)(e * N_ + n0) * D_;
    float* out_lo = out + (size_t)E_ * N_ * D_ + (size_t)(e * N_ + n0) * D_;

#pragma unroll 4
    for (int it = 0; it < TN / 8; ++it) {
        const int nl = it * 8 + rb;
        const float z0 = sZ[2 * nl + 0];   // broadcast within 32-lane group
        const float z1 = sZ[2 * nl + 1];

        f32x4 oh = z0 * w0h + z1 * w1h + bh;
        f32x4 ol = z0 * w0l + z1 * w1l + bl;

        if (act) {
            const size_t off = (size_t)nl * D_ + (size_t)d;
            __builtin_nontemporal_store(oh, (f32x4*)&out_hi[off]);
            __builtin_nontemporal_store(ol, (f32x4*)&out_lo[off]);
        }
    }
}

extern "C" void kernel_launch(void* const* d_in, const int* in_sizes, int n_in,
                              void* d_out, int out_size, void* d_ws, size_t ws_size,
                              hipStream_t stream) {
    // setup_inputs() dict order:
    // 0 inputs, 1 randsamples,
    // then for i in 0..2: enc_w{i}, enc_b{i}, hi_w{i}, hi_b{i}, lo_w{i}, lo_b{i}
    const float* inputs      = (const float*)d_in[0];
    const int*   randsamples = (const int*)d_in[1];
    const float* enc_w0 = (const float*)d_in[2];
    const float* enc_b0 = (const float*)d_in[3];
    const float* hi_w0  = (const float*)d_in[4];
    const float* hi_b0  = (const float*)d_in[5];
    const float* lo_w0  = (const float*)d_in[6];
    const float* lo_b0  = (const float*)d_in[7];
    const float* enc_w1 = (const float*)d_in[8];
    const float* enc_b1 = (const float*)d_in[9];
    const float* hi_w1  = (const float*)d_in[10];
    const float* hi_b1  = (const float*)d_in[11];
    const float* lo_w1  = (const float*)d_in[12];
    const float* lo_b1  = (const float*)d_in[13];
    const float* enc_w2 = (const float*)d_in[14];
    const float* enc_b2 = (const float*)d_in[15];
    const float* hi_w2  = (const float*)d_in[16];
    const float* hi_b2  = (const float*)d_in[17];
    const float* lo_w2  = (const float*)d_in[18];
    const float* lo_b2  = (const float*)d_in[19];

    float* ws  = (float*)d_ws;   // needs E_*WS_PER_E*4 = 249,600 bytes
    float* out = (float*)d_out;

    combine_kernel<<<E_, 128, 0, stream>>>(
        enc_w0, enc_b0, enc_w1, enc_b1, enc_w2, enc_b2,
        hi_w0, hi_b0, hi_w1, hi_b1, hi_w2, hi_b2,
        lo_w0, lo_b0, lo_w1, lo_b1, lo_w2, lo_b2, ws);

    rancoders_main<<<E_ * NTILES, 256, 0, stream>>>(inputs, randsamples, ws, out);
}

// Round 4
// 153.321 us; speedup vs baseline: 1.5404x; 1.1595x over previous
//
#include <hip/hip_runtime.h>

// Problem constants
#define E_  100
#define F_  10
#define D_  100
#define N_  8192
#define TN  256          // n-tile per block
#define NTILES (N_ / TN) // 32

typedef float f32x4 __attribute__((ext_vector_type(4)));

// d_ws float layout:
//   per-estimator combined params, e = 0..99, stride WS_PER_E:
//     [0..199]   Whi (2 x 100, a-major)   [200..299] bhi
//     [300..499] Wlo (2 x 100)            [500..599] blo
//     [600..619] Wenc (10 x 2, f-major)   [620..621] benc
//   then transposed inputs at OFF_T: inputs_T[d][n], 100 x 8192
#define OFF_WHI  0
#define OFF_BHI  200
#define OFF_WLO  300
#define OFF_BLO  500
#define OFF_WENC 600
#define OFF_BENC 620
#define WS_PER_E 624
#define OFF_T    (E_ * WS_PER_E)                  // 62400 floats
#define WS_NEED_BYTES ((size_t)(OFF_T + D_ * N_) * 4)  // 3,539,200 B

// ---------------------------------------------------------------------------
// Prep kernel: blocks 0..99 fold estimator MLPs into affine maps;
// blocks 100..163 transpose inputs (8192x100 -> 100x8192). 128 threads.
// ---------------------------------------------------------------------------
template <bool DO_TRANSPOSE>
__global__ __launch_bounds__(128) void prep_kernel(
    const float* __restrict__ inputs,
    const float* __restrict__ enc_w0, const float* __restrict__ enc_b0,
    const float* __restrict__ enc_w1, const float* __restrict__ enc_b1,
    const float* __restrict__ enc_w2, const float* __restrict__ enc_b2,
    const float* __restrict__ hi_w0,  const float* __restrict__ hi_b0,
    const float* __restrict__ hi_w1,  const float* __restrict__ hi_b1,
    const float* __restrict__ hi_w2,  const float* __restrict__ hi_b2,
    const float* __restrict__ lo_w0,  const float* __restrict__ lo_b0,
    const float* __restrict__ lo_w1,  const float* __restrict__ lo_b1,
    const float* __restrict__ lo_w2,  const float* __restrict__ lo_b2,
    float* __restrict__ ws)
{
    const int t = threadIdx.x;

    if (DO_TRANSPOSE && blockIdx.x >= E_) {
        // transpose: each block owns 128 consecutive n, all 100 d
        const int n0 = (blockIdx.x - E_) * 128;
        float* T = ws + OFF_T;
        const float* rowp = inputs + (size_t)(n0 + t) * D_;
#pragma unroll 4
        for (int d = 0; d < D_; ++d)
            T[(size_t)d * N_ + n0 + t] = rowp[d];
        return;
    }

    const int e = blockIdx.x;
    float* wsE = ws + (size_t)e * WS_PER_E;

    // ---------------- encoder: (10x5)@(5x2)@(2x2) -------------------------
    {
        const float* w0 = enc_w0 + e * 50;  // 10x5
        const float* w1 = enc_w1 + e * 10;  // 5x2
        const float* w2 = enc_w2 + e * 4;   // 2x2
        const float* b0 = enc_b0 + e * 5;
        const float* b1 = enc_b1 + e * 2;
        const float* b2 = enc_b2 + e * 2;

        __shared__ float sW01[20];  // [f][g] = w0@w1
        __shared__ float sB01[2];
        if (t < 20) {
            int f = t >> 1, g = t & 1;
            float s = 0.f;
            for (int k = 0; k < 5; ++k) s += w0[f * 5 + k] * w1[k * 2 + g];
            sW01[t] = s;
        }
        if (t < 2) {
            float s = b1[t];
            for (int k = 0; k < 5; ++k) s += b0[k] * w1[k * 2 + t];
            sB01[t] = s;
        }
        __syncthreads();
        if (t < 20) {
            int f = t >> 1, g2 = t & 1;
            wsE[OFF_WENC + t] = sW01[f * 2 + 0] * w2[0 * 2 + g2]
                              + sW01[f * 2 + 1] * w2[1 * 2 + g2];
        }
        if (t < 2) {
            wsE[OFF_BENC + t] = sB01[0] * w2[0 * 2 + t] + sB01[1] * w2[1 * 2 + t] + b2[t];
        }
        __syncthreads();
    }

    // ---------------- decoders: (2x25)@(25x50)@(50x100) -------------------
    __shared__ float sT[100];  // [a][c] = w0@w1  (2 x 50)
    __shared__ float sU[50];   // bias through layer 1
    for (int dec = 0; dec < 2; ++dec) {
        const float* w0 = (dec ? lo_w0 : hi_w0) + e * 50;    // 2x25
        const float* w1 = (dec ? lo_w1 : hi_w1) + e * 1250;  // 25x50
        const float* w2 = (dec ? lo_w2 : hi_w2) + e * 5000;  // 50x100
        const float* b0 = (dec ? lo_b0 : hi_b0) + e * 25;
        const float* b1 = (dec ? lo_b1 : hi_b1) + e * 50;
        const float* b2 = (dec ? lo_b2 : hi_b2) + e * 100;
        float* W = wsE + (dec ? OFF_WLO : OFF_WHI);
        float* B = wsE + (dec ? OFF_BLO : OFF_BHI);

        for (int i = t; i < 100; i += blockDim.x) {
            int a = i / 50, c = i % 50;
            float s = 0.f;
            for (int b = 0; b < 25; ++b) s += w0[a * 25 + b] * w1[b * 50 + c];
            sT[i] = s;
        }
        for (int i = t; i < 50; i += blockDim.x) {
            float s = b1[i];
            for (int b = 0; b < 25; ++b) s += b0[b] * w1[b * 50 + i];
            sU[i] = s;
        }
        __syncthreads();
        for (int i = t; i < 200; i += blockDim.x) {
            int a = i / 100, d = i % 100;
            float s = 0.f;
            for (int c = 0; c < 50; ++c) s += sT[a * 50 + c] * w2[c * 100 + d];
            W[i] = s;
        }
        for (int i = t; i < 100; i += blockDim.x) {
            float s = b2[i];
            for (int c = 0; c < 50; ++c) s += sU[c] * w2[c * 100 + i];
            B[i] = s;
        }
        __syncthreads();  // before sT/sU reuse by next decoder
    }
}

// ---------------------------------------------------------------------------
// Main kernel: per (e, n-tile): gather -> z (rank-2 latent) -> 2*100 outputs.
// Phase 1 reads transposed inputs (coalesced) when available.
// Phase 2: fixed column-quad per thread, weights in registers, plain stores.
// ---------------------------------------------------------------------------
template <bool USE_T>
__global__ __launch_bounds__(256) void rancoders_main(
    const float* __restrict__ inputs,      // [N, D]
    const int*   __restrict__ randsamples, // [E, F]
    const float* __restrict__ ws,
    float* __restrict__ out)               // [hi: E*N*D][lo: E*N*D]
{
    const int e    = blockIdx.x >> 5;       // / NTILES
    const int tile = blockIdx.x & (NTILES - 1);
    const int n0   = tile * TN;
    const int t    = threadIdx.x;

    __shared__ __align__(16) float sP[WS_PER_E];
    __shared__ int   sIdx[F_];
    __shared__ float sZ[TN * 2];

    const float* wsE = ws + (size_t)e * WS_PER_E;
    for (int i = t; i < 622; i += 256) sP[i] = wsE[i];
    if (t < F_) sIdx[t] = randsamples[e * F_ + t];
    __syncthreads();

    // ---- phase 1: latent z for this thread's row ----
    {
        float z0 = sP[OFF_BENC + 0];
        float z1 = sP[OFF_BENC + 1];
        if (USE_T) {
            const float* T = ws + OFF_T;
#pragma unroll
            for (int f = 0; f < F_; ++f) {
                float v = T[(size_t)sIdx[f] * N_ + n0 + t];  // coalesced
                z0 += v * sP[OFF_WENC + 2 * f + 0];
                z1 += v * sP[OFF_WENC + 2 * f + 1];
            }
        } else {
            const float* row = inputs + (size_t)(n0 + t) * D_;
#pragma unroll
            for (int f = 0; f < F_; ++f) {
                float v = row[sIdx[f]];
                z0 += v * sP[OFF_WENC + 2 * f + 0];
                z1 += v * sP[OFF_WENC + 2 * f + 1];
            }
        }
        sZ[2 * t + 0] = z0;
        sZ[2 * t + 1] = z1;
    }
    __syncthreads();

    // ---- phase 2: fixed column-quad per thread, weights in registers ----
    const int dq   = t & 31;          // 0..31; 25..31 are masked lanes
    const int rb   = t >> 5;          // row sub-index 0..7
    const bool act = (dq < 25);
    const int d    = (act ? dq : 24) * 4;   // clamp for safe LDS reads

    const f32x4 w0h = *(const f32x4*)&sP[OFF_WHI + d];
    const f32x4 w1h = *(const f32x4*)&sP[OFF_WHI + 100 + d];
    const f32x4 bh  = *(const f32x4*)&sP[OFF_BHI + d];
    const f32x4 w0l = *(const f32x4*)&sP[OFF_WLO + d];
    const f32x4 w1l = *(const f32x4*)&sP[OFF_WLO + 100 + d];
    const f32x4 bl  = *(const f32x4*)&sP[OFF_BLO + d];

    float* out_hi = out + (size_t)(e * N_ + n0) * D_;
    float* out_lo = out + (size_t)E_ * N_ * D_ + (size_t)(e * N_ + n0) * D_;

#pragma unroll 8
    for (int it = 0; it < TN / 8; ++it) {
        const int nl = it * 8 + rb;
        const float z0 = sZ[2 * nl + 0];   // broadcast within 32-lane group
        const float z1 = sZ[2 * nl + 1];

        f32x4 oh = z0 * w0h + z1 * w1h + bh;
        f32x4 ol = z0 * w0l + z1 * w1l + bl;

        if (act) {
            const size_t off = (size_t)nl * D_ + (size_t)d;
            *(f32x4*)&out_hi[off] = oh;
            *(f32x4*)&out_lo[off] = ol;
        }
    }
}

extern "C" void kernel_launch(void* const* d_in, const int* in_sizes, int n_in,
                              void* d_out, int out_size, void* d_ws, size_t ws_size,
                              hipStream_t stream) {
    const float* inputs      = (const float*)d_in[0];
    const int*   randsamples = (const int*)d_in[1];
    const float* enc_w0 = (const float*)d_in[2];
    const float* enc_b0 = (const float*)d_in[3];
    const float* hi_w0  = (const float*)d_in[4];
    const float* hi_b0  = (const float*)d_in[5];
    const float* lo_w0  = (const float*)d_in[6];
    const float* lo_b0  = (const float*)d_in[7];
    const float* enc_w1 = (const float*)d_in[8];
    const float* enc_b1 = (const float*)d_in[9];
    const float* hi_w1  = (const float*)d_in[10];
    const float* hi_b1  = (const float*)d_in[11];
    const float* lo_w1  = (const float*)d_in[12];
    const float* lo_b1  = (const float*)d_in[13];
    const float* enc_w2 = (const float*)d_in[14];
    const float* enc_b2 = (const float*)d_in[15];
    const float* hi_w2  = (const float*)d_in[16];
    const float* hi_b2  = (const float*)d_in[17];
    const float* lo_w2  = (const float*)d_in[18];
    const float* lo_b2  = (const float*)d_in[19];

    float* ws  = (float*)d_ws;
    float* out = (float*)d_out;

    const bool use_t = (ws_size >= WS_NEED_BYTES);

    if (use_t) {
        prep_kernel<true><<<E_ + N_ / 128, 128, 0, stream>>>(
            inputs,
            enc_w0, enc_b0, enc_w1, enc_b1, enc_w2, enc_b2,
            hi_w0, hi_b0, hi_w1, hi_b1, hi_w2, hi_b2,
            lo_w0, lo_b0, lo_w1, lo_b1, lo_w2, lo_b2, ws);
        rancoders_main<true><<<E_ * NTILES, 256, 0, stream>>>(
            inputs, randsamples, ws, out);
    } else {
        prep_kernel<false><<<E_, 128, 0, stream>>>(
            inputs,
            enc_w0, enc_b0, enc_w1, enc_b1, enc_w2, enc_b2,
            hi_w0, hi_b0, hi_w1, hi_b1, hi_w2, hi_b2,
            lo_w0, lo_b0, lo_w1, lo_b1, lo_w2, lo_b2, ws);
        rancoders_main<false><<<E_ * NTILES, 256, 0, stream>>>(
            inputs, randsamples, ws, out);
    }
}

// Round 5
// 150.541 us; speedup vs baseline: 1.5689x; 1.0185x over previous
//
#include <hip/hip_runtime.h>

// Problem constants
#define E_  100
#define F_  10
#define D_  100
#define N_  8192
#define TN  256          // n-tile per block
#define NTILES (N_ / TN) // 32

typedef float f32x4 __attribute__((ext_vector_type(4)));

// d_ws float layout:
//   per-estimator combined params, e = 0..99, stride WS_PER_E:
//     [0..199]   Whi (2 x 100, a-major)   [200..299] bhi
//     [300..499] Wlo (2 x 100)            [500..599] blo
//     [600..619] Wenc (10 x 2, f-major)   [620..621] benc
//   then transposed inputs at OFF_T: inputs_T[d][n], 100 x 8192
#define OFF_WHI  0
#define OFF_BHI  200
#define OFF_WLO  300
#define OFF_BLO  500
#define OFF_WENC 600
#define OFF_BENC 620
#define WS_PER_E 624
#define OFF_T    (E_ * WS_PER_E)                  // 62400 floats
#define WS_NEED_BYTES ((size_t)(OFF_T + D_ * N_) * 4)  // 3,539,200 B

// ---------------------------------------------------------------------------
// Prep kernel: blocks 0..99 fold estimator MLPs into affine maps;
// blocks 100..355 transpose inputs (8192x100 -> 100x8192), 128n x 25d tiles.
// ---------------------------------------------------------------------------
template <bool DO_TRANSPOSE>
__global__ __launch_bounds__(128) void prep_kernel(
    const float* __restrict__ inputs,
    const float* __restrict__ enc_w0, const float* __restrict__ enc_b0,
    const float* __restrict__ enc_w1, const float* __restrict__ enc_b1,
    const float* __restrict__ enc_w2, const float* __restrict__ enc_b2,
    const float* __restrict__ hi_w0,  const float* __restrict__ hi_b0,
    const float* __restrict__ hi_w1,  const float* __restrict__ hi_b1,
    const float* __restrict__ hi_w2,  const float* __restrict__ hi_b2,
    const float* __restrict__ lo_w0,  const float* __restrict__ lo_b0,
    const float* __restrict__ lo_w1,  const float* __restrict__ lo_b1,
    const float* __restrict__ lo_w2,  const float* __restrict__ lo_b2,
    float* __restrict__ ws)
{
    const int t = threadIdx.x;

    if (DO_TRANSPOSE && blockIdx.x >= E_) {
        // transpose tile: 128 consecutive n, 25 consecutive d
        const int bi = blockIdx.x - E_;          // 0..255
        const int n0 = (bi >> 2) * 128;
        const int d0 = (bi & 3) * 25;
        float* T = ws + OFF_T;
        const float* rowp = inputs + (size_t)(n0 + t) * D_ + d0;
#pragma unroll 5
        for (int j = 0; j < 25; ++j)
            T[(size_t)(d0 + j) * N_ + n0 + t] = rowp[j];
        return;
    }

    const int e = blockIdx.x;
    float* wsE = ws + (size_t)e * WS_PER_E;

    // ---------------- encoder: (10x5)@(5x2)@(2x2) -------------------------
    {
        const float* w0 = enc_w0 + e * 50;  // 10x5
        const float* w1 = enc_w1 + e * 10;  // 5x2
        const float* w2 = enc_w2 + e * 4;   // 2x2
        const float* b0 = enc_b0 + e * 5;
        const float* b1 = enc_b1 + e * 2;
        const float* b2 = enc_b2 + e * 2;

        __shared__ float sW01[20];  // [f][g] = w0@w1
        __shared__ float sB01[2];
        if (t < 20) {
            int f = t >> 1, g = t & 1;
            float s = 0.f;
            for (int k = 0; k < 5; ++k) s += w0[f * 5 + k] * w1[k * 2 + g];
            sW01[t] = s;
        }
        if (t < 2) {
            float s = b1[t];
            for (int k = 0; k < 5; ++k) s += b0[k] * w1[k * 2 + t];
            sB01[t] = s;
        }
        __syncthreads();
        if (t < 20) {
            int f = t >> 1, g2 = t & 1;
            wsE[OFF_WENC + t] = sW01[f * 2 + 0] * w2[0 * 2 + g2]
                              + sW01[f * 2 + 1] * w2[1 * 2 + g2];
        }
        if (t < 2) {
            wsE[OFF_BENC + t] = sB01[0] * w2[0 * 2 + t] + sB01[1] * w2[1 * 2 + t] + b2[t];
        }
        __syncthreads();
    }

    // ---------------- decoders: (2x25)@(25x50)@(50x100) -------------------
    __shared__ float sT[100];  // [a][c] = w0@w1  (2 x 50)
    __shared__ float sU[50];   // bias through layer 1
    for (int dec = 0; dec < 2; ++dec) {
        const float* w0 = (dec ? lo_w0 : hi_w0) + e * 50;    // 2x25
        const float* w1 = (dec ? lo_w1 : hi_w1) + e * 1250;  // 25x50
        const float* w2 = (dec ? lo_w2 : hi_w2) + e * 5000;  // 50x100
        const float* b0 = (dec ? lo_b0 : hi_b0) + e * 25;
        const float* b1 = (dec ? lo_b1 : hi_b1) + e * 50;
        const float* b2 = (dec ? lo_b2 : hi_b2) + e * 100;
        float* W = wsE + (dec ? OFF_WLO : OFF_WHI);
        float* B = wsE + (dec ? OFF_BLO : OFF_BHI);

        for (int i = t; i < 100; i += blockDim.x) {
            int a = i / 50, c = i % 50;
            float s = 0.f;
            for (int b = 0; b < 25; ++b) s += w0[a * 25 + b] * w1[b * 50 + c];
            sT[i] = s;
        }
        for (int i = t; i < 50; i += blockDim.x) {
            float s = b1[i];
            for (int b = 0; b < 25; ++b) s += b0[b] * w1[b * 50 + i];
            sU[i] = s;
        }
        __syncthreads();
        for (int i = t; i < 200; i += blockDim.x) {
            int a = i / 100, d = i % 100;
            float s = 0.f;
            for (int c = 0; c < 50; ++c) s += sT[a * 50 + c] * w2[c * 100 + d];
            W[i] = s;
        }
        for (int i = t; i < 100; i += blockDim.x) {
            float s = b2[i];
            for (int c = 0; c < 50; ++c) s += sU[c] * w2[c * 100 + i];
            B[i] = s;
        }
        __syncthreads();  // before sT/sU reuse by next decoder
    }
}

// ---------------------------------------------------------------------------
// Main kernel: per (e, n-tile): gather -> z (rank-2 latent) -> 2*100 outputs.
// Phase 2: each WAVE owns an aligned 1600B chunk (4 rows) per iteration,
// written by back-to-back stores from the same wave (offset immediates off one
// base) so every 64B-line split is intra-wave and merges in L2 before
// eviction. Weights live in registers; LDS traffic is z broadcasts only.
// ---------------------------------------------------------------------------
template <bool USE_T>
__global__ __launch_bounds__(256) void rancoders_main(
    const float* __restrict__ inputs,      // [N, D]
    const int*   __restrict__ randsamples, // [E, F]
    const float* __restrict__ ws,
    float* __restrict__ out)               // [hi: E*N*D][lo: E*N*D]
{
    const int e    = blockIdx.x >> 5;       // / NTILES
    const int tile = blockIdx.x & (NTILES - 1);
    const int n0   = tile * TN;
    const int t    = threadIdx.x;

    __shared__ __align__(16) float sP[WS_PER_E];
    __shared__ int    sIdx[F_];
    __shared__ float2 sZ2[TN];

    const float* wsE = ws + (size_t)e * WS_PER_E;
    for (int i = t; i < 622; i += 256) sP[i] = wsE[i];
    if (t < F_) sIdx[t] = randsamples[e * F_ + t];
    __syncthreads();

    // ---- phase 1: latent z for this thread's row ----
    {
        float z0 = sP[OFF_BENC + 0];
        float z1 = sP[OFF_BENC + 1];
        if (USE_T) {
            const float* T = ws + OFF_T;
#pragma unroll
            for (int f = 0; f < F_; ++f) {
                float v = T[(size_t)sIdx[f] * N_ + n0 + t];  // coalesced
                z0 += v * sP[OFF_WENC + 2 * f + 0];
                z1 += v * sP[OFF_WENC + 2 * f + 1];
            }
        } else {
            const float* row = inputs + (size_t)(n0 + t) * D_;
#pragma unroll
            for (int f = 0; f < F_; ++f) {
                float v = row[sIdx[f]];
                z0 += v * sP[OFF_WENC + 2 * f + 0];
                z1 += v * sP[OFF_WENC + 2 * f + 1];
            }
        }
        sZ2[t] = make_float2(z0, z1);
    }
    __syncthreads();

    // ---- phase 2: aligned 1600B chunk per wave per iteration ----
    const int w    = t >> 6;          // wave 0..3
    const int l    = t & 63;
    const int h    = l >> 5;          // half-wave 0/1
    const int dq   = l & 31;          // 0..31; 25..31 masked
    const bool act = (dq < 25);
    const int d    = (act ? dq : 24) * 4;   // clamp for safe LDS reads

    const f32x4 w0h = *(const f32x4*)&sP[OFF_WHI + d];
    const f32x4 w1h = *(const f32x4*)&sP[OFF_WHI + 100 + d];
    const f32x4 bh  = *(const f32x4*)&sP[OFF_BHI + d];
    const f32x4 w0l = *(const f32x4*)&sP[OFF_WLO + d];
    const f32x4 w1l = *(const f32x4*)&sP[OFF_WLO + 100 + d];
    const f32x4 bl  = *(const f32x4*)&sP[OFF_BLO + d];

    float* out_hi = out + (size_t)(e * N_ + n0) * D_;
    float* out_lo = out + (size_t)E_ * N_ * D_ + (size_t)(e * N_ + n0) * D_;

    // wave w handles rows it*16 + w*4 .. +3 each iteration (1600B aligned):
    //   store 1: rows +h (this lane), store 2: rows +2+h. 16 iterations.
#pragma unroll 8
    for (int it = 0; it < TN / 16; ++it) {
        const int r0 = it * 16 + w * 4 + h;     // lane's first row
        const float2 za = sZ2[r0];              // broadcast per half-wave
        const float2 zb = sZ2[r0 + 2];

        f32x4 oha = za.x * w0h + za.y * w1h + bh;
        f32x4 ohb = zb.x * w0h + zb.y * w1h + bh;
        f32x4 ola = za.x * w0l + za.y * w1l + bl;
        f32x4 olb = zb.x * w0l + zb.y * w1l + bl;

        if (act) {
            const size_t off = (size_t)r0 * D_ + (size_t)d;
            *(f32x4*)&out_hi[off]            = oha;   // same base, +800B imm
            *(f32x4*)&out_hi[off + 2 * D_]   = ohb;
            *(f32x4*)&out_lo[off]            = ola;
            *(f32x4*)&out_lo[off + 2 * D_]   = olb;
        }
    }
}

extern "C" void kernel_launch(void* const* d_in, const int* in_sizes, int n_in,
                              void* d_out, int out_size, void* d_ws, size_t ws_size,
                              hipStream_t stream) {
    const float* inputs      = (const float*)d_in[0];
    const int*   randsamples = (const int*)d_in[1];
    const float* enc_w0 = (const float*)d_in[2];
    const float* enc_b0 = (const float*)d_in[3];
    const float* hi_w0  = (const float*)d_in[4];
    const float* hi_b0  = (const float*)d_in[5];
    const float* lo_w0  = (const float*)d_in[6];
    const float* lo_b0  = (const float*)d_in[7];
    const float* enc_w1 = (const float*)d_in[8];
    const float* enc_b1 = (const float*)d_in[9];
    const float* hi_w1  = (const float*)d_in[10];
    const float* hi_b1  = (const float*)d_in[11];
    const float* lo_w1  = (const float*)d_in[12];
    const float* lo_b1  = (const float*)d_in[13];
    const float* enc_w2 = (const float*)d_in[14];
    const float* enc_b2 = (const float*)d_in[15];
    const float* hi_w2  = (const float*)d_in[16];
    const float* hi_b2  = (const float*)d_in[17];
    const float* lo_w2  = (const float*)d_in[18];
    const float* lo_b2  = (const float*)d_in[19];

    float* ws  = (float*)d_ws;
    float* out = (float*)d_out;

    const bool use_t = (ws_size >= WS_NEED_BYTES);

    if (use_t) {
        prep_kernel<true><<<E_ + 256, 128, 0, stream>>>(
            inputs,
            enc_w0, enc_b0, enc_w1, enc_b1, enc_w2, enc_b2,
            hi_w0, hi_b0, hi_w1, hi_b1, hi_w2, hi_b2,
            lo_w0, lo_b0, lo_w1, lo_b1, lo_w2, lo_b2, ws);
        rancoders_main<true><<<E_ * NTILES, 256, 0, stream>>>(
            inputs, randsamples, ws, out);
    } else {
        prep_kernel<false><<<E_, 128, 0, stream>>>(
            inputs,
            enc_w0, enc_b0, enc_w1, enc_b1, enc_w2, enc_b2,
            hi_w0, hi_b0, hi_w1, hi_b1, hi_w2, hi_b2,
            lo_w0, lo_b0, lo_w1, lo_b1, lo_w2, lo_b2, ws);
        rancoders_main<false><<<E_ * NTILES, 256, 0, stream>>>(
            inputs, randsamples, ws, out);
    }
}

// Round 6
// 148.490 us; speedup vs baseline: 1.5905x; 1.0138x over previous
//
#include <hip/hip_runtime.h>

// Problem constants
#define E_  100
#define F_  10
#define D_  100
#define N_  8192
#define TN  256          // n-tile per block
#define NTILES (N_ / TN) // 32
#define CHUNK 64         // rows staged in LDS per copy-out round

typedef float f32x4 __attribute__((ext_vector_type(4)));

// d_ws float layout:
//   per-estimator combined params, e = 0..99, stride WS_PER_E:
//     [0..199]   Whi (2 x 100, a-major)   [200..299] bhi
//     [300..499] Wlo (2 x 100)            [500..599] blo
//     [600..619] Wenc (10 x 2, f-major)   [620..621] benc
//   then transposed inputs at OFF_T: inputs_T[d][n], 100 x 8192
#define OFF_WHI  0
#define OFF_BHI  200
#define OFF_WLO  300
#define OFF_BLO  500
#define OFF_WENC 600
#define OFF_BENC 620
#define WS_PER_E 624
#define OFF_T    (E_ * WS_PER_E)                  // 62400 floats
#define WS_NEED_BYTES ((size_t)(OFF_T + D_ * N_) * 4)  // 3,539,200 B

// ---------------------------------------------------------------------------
// Prep kernel: blocks 0..99 fold estimator MLPs into affine maps;
// blocks 100..355 transpose inputs (8192x100 -> 100x8192), 128n x 25d tiles.
// ---------------------------------------------------------------------------
template <bool DO_TRANSPOSE>
__global__ __launch_bounds__(128) void prep_kernel(
    const float* __restrict__ inputs,
    const float* __restrict__ enc_w0, const float* __restrict__ enc_b0,
    const float* __restrict__ enc_w1, const float* __restrict__ enc_b1,
    const float* __restrict__ enc_w2, const float* __restrict__ enc_b2,
    const float* __restrict__ hi_w0,  const float* __restrict__ hi_b0,
    const float* __restrict__ hi_w1,  const float* __restrict__ hi_b1,
    const float* __restrict__ hi_w2,  const float* __restrict__ hi_b2,
    const float* __restrict__ lo_w0,  const float* __restrict__ lo_b0,
    const float* __restrict__ lo_w1,  const float* __restrict__ lo_b1,
    const float* __restrict__ lo_w2,  const float* __restrict__ lo_b2,
    float* __restrict__ ws)
{
    const int t = threadIdx.x;

    if (DO_TRANSPOSE && blockIdx.x >= E_) {
        // transpose tile: 128 consecutive n, 25 consecutive d
        const int bi = blockIdx.x - E_;          // 0..255
        const int n0 = (bi >> 2) * 128;
        const int d0 = (bi & 3) * 25;
        float* T = ws + OFF_T;
        const float* rowp = inputs + (size_t)(n0 + t) * D_ + d0;
#pragma unroll 5
        for (int j = 0; j < 25; ++j)
            T[(size_t)(d0 + j) * N_ + n0 + t] = rowp[j];
        return;
    }

    const int e = blockIdx.x;
    float* wsE = ws + (size_t)e * WS_PER_E;

    // ---------------- encoder: (10x5)@(5x2)@(2x2) -------------------------
    {
        const float* w0 = enc_w0 + e * 50;  // 10x5
        const float* w1 = enc_w1 + e * 10;  // 5x2
        const float* w2 = enc_w2 + e * 4;   // 2x2
        const float* b0 = enc_b0 + e * 5;
        const float* b1 = enc_b1 + e * 2;
        const float* b2 = enc_b2 + e * 2;

        __shared__ float sW01[20];  // [f][g] = w0@w1
        __shared__ float sB01[2];
        if (t < 20) {
            int f = t >> 1, g = t & 1;
            float s = 0.f;
            for (int k = 0; k < 5; ++k) s += w0[f * 5 + k] * w1[k * 2 + g];
            sW01[t] = s;
        }
        if (t < 2) {
            float s = b1[t];
            for (int k = 0; k < 5; ++k) s += b0[k] * w1[k * 2 + t];
            sB01[t] = s;
        }
        __syncthreads();
        if (t < 20) {
            int f = t >> 1, g2 = t & 1;
            wsE[OFF_WENC + t] = sW01[f * 2 + 0] * w2[0 * 2 + g2]
                              + sW01[f * 2 + 1] * w2[1 * 2 + g2];
        }
        if (t < 2) {
            wsE[OFF_BENC + t] = sB01[0] * w2[0 * 2 + t] + sB01[1] * w2[1 * 2 + t] + b2[t];
        }
        __syncthreads();
    }

    // ---------------- decoders: (2x25)@(25x50)@(50x100) -------------------
    __shared__ float sT[100];  // [a][c] = w0@w1  (2 x 50)
    __shared__ float sU[50];   // bias through layer 1
    for (int dec = 0; dec < 2; ++dec) {
        const float* w0 = (dec ? lo_w0 : hi_w0) + e * 50;    // 2x25
        const float* w1 = (dec ? lo_w1 : hi_w1) + e * 1250;  // 25x50
        const float* w2 = (dec ? lo_w2 : hi_w2) + e * 5000;  // 50x100
        const float* b0 = (dec ? lo_b0 : hi_b0) + e * 25;
        const float* b1 = (dec ? lo_b1 : hi_b1) + e * 50;
        const float* b2 = (dec ? lo_b2 : hi_b2) + e * 100;
        float* W = wsE + (dec ? OFF_WLO : OFF_WHI);
        float* B = wsE + (dec ? OFF_BLO : OFF_BHI);

        for (int i = t; i < 100; i += blockDim.x) {
            int a = i / 50, c = i % 50;
            float s = 0.f;
            for (int b = 0; b < 25; ++b) s += w0[a * 25 + b] * w1[b * 50 + c];
            sT[i] = s;
        }
        for (int i = t; i < 50; i += blockDim.x) {
            float s = b1[i];
            for (int b = 0; b < 25; ++b) s += b0[b] * w1[b * 50 + i];
            sU[i] = s;
        }
        __syncthreads();
        for (int i = t; i < 200; i += blockDim.x) {
            int a = i / 100, d = i % 100;
            float s = 0.f;
            for (int c = 0; c < 50; ++c) s += sT[a * 50 + c] * w2[c * 100 + d];
            W[i] = s;
        }
        for (int i = t; i < 100; i += blockDim.x) {
            float s = b2[i];
            for (int c = 0; c < 50; ++c) s += sU[c] * w2[c * 100 + i];
            B[i] = s;
        }
        __syncthreads();  // before sT/sU reuse by next decoder
    }
}

// ---------------------------------------------------------------------------
// Main kernel: per (e, n-tile): gather -> z (rank-2 latent) -> 2*100 outputs.
// Phase 2: compute 64-row chunks into an LDS stage (weights in registers,
// masked lanes hit LDS only), then a PURE dense copy-out: all-64-lane f32x4
// stores, contiguous and sequential -- identical store shape to the 6.8 TB/s
// fill kernel, with no compute interleaved between stores.
// ---------------------------------------------------------------------------
template <bool USE_T>
__global__ __launch_bounds__(256) void rancoders_main(
    const float* __restrict__ inputs,      // [N, D]
    const int*   __restrict__ randsamples, // [E, F]
    const float* __restrict__ ws,
    float* __restrict__ out)               // [hi: E*N*D][lo: E*N*D]
{
    const int e    = blockIdx.x >> 5;       // / NTILES
    const int tile = blockIdx.x & (NTILES - 1);
    const int n0   = tile * TN;
    const int t    = threadIdx.x;

    __shared__ __align__(16) float sP[WS_PER_E];
    __shared__ int    sIdx[F_];
    __shared__ float2 sZ2[TN];
    __shared__ __align__(16) float sStage[CHUNK * D_];   // 25,600 B

    const float* wsE = ws + (size_t)e * WS_PER_E;
    for (int i = t; i < 622; i += 256) sP[i] = wsE[i];
    if (t < F_) sIdx[t] = randsamples[e * F_ + t];
    __syncthreads();

    // ---- phase 1: latent z for this thread's row ----
    {
        float z0 = sP[OFF_BENC + 0];
        float z1 = sP[OFF_BENC + 1];
        if (USE_T) {
            const float* T = ws + OFF_T;
#pragma unroll
            for (int f = 0; f < F_; ++f) {
                float v = T[(size_t)sIdx[f] * N_ + n0 + t];  // coalesced
                z0 += v * sP[OFF_WENC + 2 * f + 0];
                z1 += v * sP[OFF_WENC + 2 * f + 1];
            }
        } else {
            const float* row = inputs + (size_t)(n0 + t) * D_;
#pragma unroll
            for (int f = 0; f < F_; ++f) {
                float v = row[sIdx[f]];
                z0 += v * sP[OFF_WENC + 2 * f + 0];
                z1 += v * sP[OFF_WENC + 2 * f + 1];
            }
        }
        sZ2[t] = make_float2(z0, z1);
    }

    // ---- phase 2 prep: per-lane weight registers ----
    const int w    = t >> 6;          // wave 0..3
    const int l    = t & 63;
    const int h    = l >> 5;          // half-wave 0/1
    const int dq   = l & 31;          // 0..31; 25..31 masked
    const bool act = (dq < 25);
    const int d    = (act ? dq : 24) * 4;   // clamp for safe LDS reads

    const f32x4 w0h = *(const f32x4*)&sP[OFF_WHI + d];
    const f32x4 w1h = *(const f32x4*)&sP[OFF_WHI + 100 + d];
    const f32x4 bh  = *(const f32x4*)&sP[OFF_BHI + d];
    const f32x4 w0l = *(const f32x4*)&sP[OFF_WLO + d];
    const f32x4 w1l = *(const f32x4*)&sP[OFF_WLO + 100 + d];
    const f32x4 bl  = *(const f32x4*)&sP[OFF_BLO + d];

    __syncthreads();

    float* out_hi = out + (size_t)(e * N_ + n0) * D_;
    float* out_lo = out + (size_t)E_ * N_ * D_ + (size_t)(e * N_ + n0) * D_;

    for (int half = 0; half < 2; ++half) {
        const f32x4 w0 = half ? w0l : w0h;
        const f32x4 w1 = half ? w1l : w1h;
        const f32x4 bb = half ? bl  : bh;
        float* dst_base = half ? out_lo : out_hi;

        for (int c = 0; c < TN / CHUNK; ++c) {
            // -- compute chunk rows [c*64, c*64+64) into LDS stage --
#pragma unroll
            for (int it = 0; it < CHUNK / 16; ++it) {
                const int rl = it * 16 + w * 4 + h;       // local row 0..63
                const float2 za = sZ2[c * CHUNK + rl];
                const float2 zb = sZ2[c * CHUNK + rl + 2];
                f32x4 oa = za.x * w0 + za.y * w1 + bb;
                f32x4 ob = zb.x * w0 + zb.y * w1 + bb;
                if (act) {
                    *(f32x4*)&sStage[rl * D_ + d]       = oa;
                    *(f32x4*)&sStage[(rl + 2) * D_ + d] = ob;
                }
            }
            __syncthreads();

            // -- dense copy-out: 1600 quads, all-lane f32x4 stores --
            float* dst = dst_base + (size_t)(c * CHUNK) * D_;
#pragma unroll
            for (int k = 0; k < 7; ++k) {
                const int q = k * 256 + t;
                if (q < (CHUNK * D_) / 4) {
                    f32x4 v = *(const f32x4*)&sStage[q * 4];
                    *(f32x4*)&dst[(size_t)q * 4] = v;
                }
            }
            __syncthreads();   // before stage reuse
        }
    }
}

extern "C" void kernel_launch(void* const* d_in, const int* in_sizes, int n_in,
                              void* d_out, int out_size, void* d_ws, size_t ws_size,
                              hipStream_t stream) {
    const float* inputs      = (const float*)d_in[0];
    const int*   randsamples = (const int*)d_in[1];
    const float* enc_w0 = (const float*)d_in[2];
    const float* enc_b0 = (const float*)d_in[3];
    const float* hi_w0  = (const float*)d_in[4];
    const float* hi_b0  = (const float*)d_in[5];
    const float* lo_w0  = (const float*)d_in[6];
    const float* lo_b0  = (const float*)d_in[7];
    const float* enc_w1 = (const float*)d_in[8];
    const float* enc_b1 = (const float*)d_in[9];
    const float* hi_w1  = (const float*)d_in[10];
    const float* hi_b1  = (const float*)d_in[11];
    const float* lo_w1  = (const float*)d_in[12];
    const float* lo_b1  = (const float*)d_in[13];
    const float* enc_w2 = (const float*)d_in[14];
    const float* enc_b2 = (const float*)d_in[15];
    const float* hi_w2  = (const float*)d_in[16];
    const float* hi_b2  = (const float*)d_in[17];
    const float* lo_w2  = (const float*)d_in[18];
    const float* lo_b2  = (const float*)d_in[19];

    float* ws  = (float*)d_ws;
    float* out = (float*)d_out;

    const bool use_t = (ws_size >= WS_NEED_BYTES);

    if (use_t) {
        prep_kernel<true><<<E_ + 256, 128, 0, stream>>>(
            inputs,
            enc_w0, enc_b0, enc_w1, enc_b1, enc_w2, enc_b2,
            hi_w0, hi_b0, hi_w1, hi_b1, hi_w2, hi_b2,
            lo_w0, lo_b0, lo_w1, lo_b1, lo_w2, lo_b2, ws);
        rancoders_main<true><<<E_ * NTILES, 256, 0, stream>>>(
            inputs, randsamples, ws, out);
    } else {
        prep_kernel<false><<<E_, 128, 0, stream>>>(
            inputs,
            enc_w0, enc_b0, enc_w1, enc_b1, enc_w2, enc_b2,
            hi_w0, hi_b0, hi_w1, hi_b1, hi_w2, hi_b2,
            lo_w0, lo_b0, lo_w1, lo_b1, lo_w2, lo_b2, ws);
        rancoders_main<false><<<E_ * NTILES, 256, 0, stream>>>(
            inputs, randsamples, ws, out);
    }
}